// Round 1
// baseline (67.636 us; speedup 1.0000x reference)
//
#include <hip/hip_runtime.h>
#include <math.h>

#define NN 4096
#define NE 131072
#define C 128
#define NH 8
#define HD 16

// ---------------- QKV projection: Q/K/V = x @ W + b ----------------
__global__ __launch_bounds__(256) void qkv_kernel(
    const float* __restrict__ x,
    const float* __restrict__ Wq, const float* __restrict__ bq,
    const float* __restrict__ Wk, const float* __restrict__ bk,
    const float* __restrict__ Wv, const float* __restrict__ bv,
    float* __restrict__ Q, float* __restrict__ K, float* __restrict__ V)
{
    __shared__ float xs[16][C];
    const int n0 = blockIdx.x * 16;
    for (int i = threadIdx.x; i < 16 * C; i += 256)
        xs[i >> 7][i & 127] = x[n0 * C + i];
    __syncthreads();

    const int c = threadIdx.x & 127;
    const int half = threadIdx.x >> 7;   // 0 or 1 -> nodes half*8 .. +8
    float aq[8], ak[8], av[8];
    #pragma unroll
    for (int j = 0; j < 8; j++) { aq[j] = 0.f; ak[j] = 0.f; av[j] = 0.f; }

    for (int k = 0; k < C; k++) {
        const float wq = Wq[k * C + c];
        const float wk = Wk[k * C + c];
        const float wv = Wv[k * C + c];
        #pragma unroll
        for (int j = 0; j < 8; j++) {
            const float xv = xs[half * 8 + j][k];
            aq[j] = fmaf(xv, wq, aq[j]);
            ak[j] = fmaf(xv, wk, ak[j]);
            av[j] = fmaf(xv, wv, av[j]);
        }
    }
    const float bqv = bq[c], bkv = bk[c], bvv = bv[c];
    #pragma unroll
    for (int j = 0; j < 8; j++) {
        const int n = n0 + half * 8 + j;
        Q[n * C + c] = aq[j] + bqv;
        K[n * C + c] = ak[j] + bkv;
        V[n * C + c] = av[j] + bvv;
    }
}

// ---------------- adjacency bitmask build (dedupes edges) ----------------
__global__ __launch_bounds__(256) void mask_kernel(
    const int* __restrict__ ei, unsigned int* __restrict__ mask)
{
    const int e = blockIdx.x * 256 + threadIdx.x;
    if (e < NE) {
        int src = ei[e];
        int dst = ei[NE + e];
        src = src < 0 ? 0 : (src > NN - 1 ? NN - 1 : src);
        dst = dst < 0 ? 0 : (dst > NN - 1 ? NN - 1 : dst);
        atomicOr(&mask[(src * NN + dst) >> 5], 1u << (dst & 31));
    }
}

// ---------------- sparse attention: 1 wave (64 lanes) per node ----------------
// lane = sub*8 + h : 8 lanes per head, 8 heads.
__global__ __launch_bounds__(64) void attn_kernel(
    const float* __restrict__ Q, const float* __restrict__ K,
    const float* __restrict__ V, const unsigned int* __restrict__ mask,
    float* __restrict__ attn_out)
{
    __shared__ unsigned short nb[NN];
    __shared__ int cnt_s;
    const int n = blockIdx.x;
    const int lane = threadIdx.x;
    if (lane == 0) cnt_s = 0;
    __syncthreads();

    // enumerate neighbor set from bitmask row (128 x u32 words)
    const unsigned int* row = mask + n * (NN / 32);
    #pragma unroll
    for (int j = 0; j < 2; j++) {
        const int w = lane * 2 + j;
        unsigned int bits = row[w];
        if (bits) {
            int off = atomicAdd(&cnt_s, __popc(bits));
            while (bits) {
                const int b = __ffs(bits) - 1;
                bits &= bits - 1;
                nb[off++] = (unsigned short)(w * 32 + b);
            }
        }
    }
    __syncthreads();
    const int deg = cnt_s;
    const int h = lane & 7;
    const int sub = lane >> 3;

    // Q fragment for this head
    float qh[16];
    {
        const float4* qp = reinterpret_cast<const float4*>(Q + n * C + h * HD);
        const float4 q0 = qp[0], q1 = qp[1], q2 = qp[2], q3 = qp[3];
        qh[0]=q0.x; qh[1]=q0.y; qh[2]=q0.z; qh[3]=q0.w;
        qh[4]=q1.x; qh[5]=q1.y; qh[6]=q1.z; qh[7]=q1.w;
        qh[8]=q2.x; qh[9]=q2.y; qh[10]=q2.z; qh[11]=q2.w;
        qh[12]=q3.x; qh[13]=q3.y; qh[14]=q3.z; qh[15]=q3.w;
    }

    // pass A: online max + sum of exp
    float mmax = -INFINITY, ssum = 0.f;
    for (int i = sub; i < deg; i += 8) {
        const int m = nb[i];
        const float4* kp = reinterpret_cast<const float4*>(K + m * C + h * HD);
        const float4 k0 = kp[0], k1 = kp[1], k2 = kp[2], k3 = kp[3];
        float s = qh[0]*k0.x + qh[1]*k0.y + qh[2]*k0.z + qh[3]*k0.w
                + qh[4]*k1.x + qh[5]*k1.y + qh[6]*k1.z + qh[7]*k1.w
                + qh[8]*k2.x + qh[9]*k2.y + qh[10]*k2.z + qh[11]*k2.w
                + qh[12]*k3.x + qh[13]*k3.y + qh[14]*k3.z + qh[15]*k3.w;
        s *= 0.25f;
        const float nm = fmaxf(mmax, s);
        ssum = ssum * __expf(mmax - nm) + __expf(s - nm);
        mmax = nm;
    }
    // butterfly combine across the 8 sub-lanes of each head
    #pragma unroll
    for (int off = 8; off < 64; off <<= 1) {
        const float omax = __shfl_xor(mmax, off, 64);
        const float osum = __shfl_xor(ssum, off, 64);
        const float nm = fmaxf(mmax, omax);
        if (nm != -INFINITY)
            ssum = ssum * __expf(mmax - nm) + osum * __expf(omax - nm);
        else
            ssum = ssum + osum;
        mmax = nm;
    }

    const float inv = (ssum > 0.f) ? 1.f / ssum : 0.f;

    // pass B: recompute score, accumulate p * V
    float acc[16];
    #pragma unroll
    for (int d = 0; d < 16; d++) acc[d] = 0.f;
    for (int i = sub; i < deg; i += 8) {
        const int m = nb[i];
        const float4* kp = reinterpret_cast<const float4*>(K + m * C + h * HD);
        const float4 k0 = kp[0], k1 = kp[1], k2 = kp[2], k3 = kp[3];
        float s = qh[0]*k0.x + qh[1]*k0.y + qh[2]*k0.z + qh[3]*k0.w
                + qh[4]*k1.x + qh[5]*k1.y + qh[6]*k1.z + qh[7]*k1.w
                + qh[8]*k2.x + qh[9]*k2.y + qh[10]*k2.z + qh[11]*k2.w
                + qh[12]*k3.x + qh[13]*k3.y + qh[14]*k3.z + qh[15]*k3.w;
        const float p = __expf(s * 0.25f - mmax) * inv;
        const float4* vp = reinterpret_cast<const float4*>(V + m * C + h * HD);
        const float4 v0 = vp[0], v1 = vp[1], v2 = vp[2], v3 = vp[3];
        acc[0]  = fmaf(p, v0.x, acc[0]);  acc[1]  = fmaf(p, v0.y, acc[1]);
        acc[2]  = fmaf(p, v0.z, acc[2]);  acc[3]  = fmaf(p, v0.w, acc[3]);
        acc[4]  = fmaf(p, v1.x, acc[4]);  acc[5]  = fmaf(p, v1.y, acc[5]);
        acc[6]  = fmaf(p, v1.z, acc[6]);  acc[7]  = fmaf(p, v1.w, acc[7]);
        acc[8]  = fmaf(p, v2.x, acc[8]);  acc[9]  = fmaf(p, v2.y, acc[9]);
        acc[10] = fmaf(p, v2.z, acc[10]); acc[11] = fmaf(p, v2.w, acc[11]);
        acc[12] = fmaf(p, v3.x, acc[12]); acc[13] = fmaf(p, v3.y, acc[13]);
        acc[14] = fmaf(p, v3.z, acc[14]); acc[15] = fmaf(p, v3.w, acc[15]);
    }
    #pragma unroll
    for (int off = 8; off < 64; off <<= 1) {
        #pragma unroll
        for (int d = 0; d < 16; d++)
            acc[d] += __shfl_xor(acc[d], off, 64);
    }

    if (deg > 0) {
        if (sub == 0) {
            float4* op = reinterpret_cast<float4*>(attn_out + n * C + h * HD);
            op[0] = make_float4(acc[0],  acc[1],  acc[2],  acc[3]);
            op[1] = make_float4(acc[4],  acc[5],  acc[6],  acc[7]);
            op[2] = make_float4(acc[8],  acc[9],  acc[10], acc[11]);
            op[3] = make_float4(acc[12], acc[13], acc[14], acc[15]);
        }
    } else {
        // all-masked row: attention = 1/n uniform -> mean of V per channel
        float s0 = 0.f, s1 = 0.f;
        for (int m = 0; m < NN; m++) {
            s0 += V[m * C + lane];
            s1 += V[m * C + 64 + lane];
        }
        attn_out[n * C + lane]      = s0 * (1.f / (float)NN);
        attn_out[n * C + 64 + lane] = s1 * (1.f / (float)NN);
    }
}

// ---------------- output projection: out = attn @ Wo + bo ----------------
__global__ __launch_bounds__(256) void proj_kernel(
    const float* __restrict__ a, const float* __restrict__ Wo,
    const float* __restrict__ bo, float* __restrict__ out)
{
    __shared__ float as[16][C];
    const int n0 = blockIdx.x * 16;
    for (int i = threadIdx.x; i < 16 * C; i += 256)
        as[i >> 7][i & 127] = a[n0 * C + i];
    __syncthreads();

    const int c = threadIdx.x & 127;
    const int half = threadIdx.x >> 7;
    float ac[8];
    #pragma unroll
    for (int j = 0; j < 8; j++) ac[j] = 0.f;
    for (int k = 0; k < C; k++) {
        const float w = Wo[k * C + c];
        #pragma unroll
        for (int j = 0; j < 8; j++)
            ac[j] = fmaf(as[half * 8 + j][k], w, ac[j]);
    }
    const float bv = bo[c];
    #pragma unroll
    for (int j = 0; j < 8; j++)
        out[(n0 + half * 8 + j) * C + c] = ac[j] + bv;
}

extern "C" void kernel_launch(void* const* d_in, const int* in_sizes, int n_in,
                              void* d_out, int out_size, void* d_ws, size_t ws_size,
                              hipStream_t stream)
{
    const float* x  = (const float*)d_in[0];
    const int*   ei = (const int*)d_in[1];
    const float* Wq = (const float*)d_in[2];
    const float* bq = (const float*)d_in[3];
    const float* Wk = (const float*)d_in[4];
    const float* bk = (const float*)d_in[5];
    const float* Wv = (const float*)d_in[6];
    const float* bv = (const float*)d_in[7];
    const float* Wo = (const float*)d_in[8];
    const float* bo = (const float*)d_in[9];
    float* out = (float*)d_out;

    char* ws = (char*)d_ws;
    const size_t MB2 = 1u << 21;           // 2 MiB = 4096*128*4
    float*        Q    = (float*)(ws);
    float*        K    = (float*)(ws + MB2);
    float*        V    = (float*)(ws + 2 * MB2);
    float*        attn = (float*)(ws + 3 * MB2);
    unsigned int* mask = (unsigned int*)(ws + 4 * MB2);

    hipMemsetAsync(mask, 0, NN * (NN / 8), stream);   // 2 MiB bitmask
    qkv_kernel<<<NN / 16, 256, 0, stream>>>(x, Wq, bq, Wk, bk, Wv, bv, Q, K, V);
    mask_kernel<<<NE / 256, 256, 0, stream>>>(ei, mask);
    attn_kernel<<<NN, 64, 0, stream>>>(Q, K, V, mask, attn);
    proj_kernel<<<NN / 16, 256, 0, stream>>>(attn, Wo, bo, out);
}

// Round 2
// 62.251 us; speedup vs baseline: 1.0865x; 1.0865x over previous
//
#include <hip/hip_runtime.h>
#include <math.h>

#define NN 4096
#define NE 131072
#define C 128
#define NH 8
#define HD 16

// ---------------- QKV projection: Q/K/V = x @ W + b  (+ mask clear) ----------------
// 256 blocks; each block also zeroes an 8 KiB slice of the 2 MiB adjacency bitmask,
// replacing the pathologically slow rocclr fillBufferAligned (~42 us) seen in R1.
__global__ __launch_bounds__(256) void qkv_kernel(
    const float* __restrict__ x,
    const float* __restrict__ Wq, const float* __restrict__ bq,
    const float* __restrict__ Wk, const float* __restrict__ bk,
    const float* __restrict__ Wv, const float* __restrict__ bv,
    float* __restrict__ Q, float* __restrict__ K, float* __restrict__ V,
    float4* __restrict__ mask_clear)   // 2 MiB region viewed as float4
{
    // clear my slice of the mask: 8 KiB/block = 512 float4 = 2 per thread
    {
        float4 z = make_float4(0.f, 0.f, 0.f, 0.f);
        float4* p = mask_clear + (size_t)blockIdx.x * 512;
        p[threadIdx.x]       = z;
        p[threadIdx.x + 256] = z;
    }

    __shared__ float xs[16][C];
    const int n0 = blockIdx.x * 16;
    for (int i = threadIdx.x; i < 16 * C; i += 256)
        xs[i >> 7][i & 127] = x[n0 * C + i];
    __syncthreads();

    const int c = threadIdx.x & 127;
    const int half = threadIdx.x >> 7;   // 0 or 1 -> nodes half*8 .. +8
    float aq[8], ak[8], av[8];
    #pragma unroll
    for (int j = 0; j < 8; j++) { aq[j] = 0.f; ak[j] = 0.f; av[j] = 0.f; }

    for (int k = 0; k < C; k++) {
        const float wq = Wq[k * C + c];
        const float wk = Wk[k * C + c];
        const float wv = Wv[k * C + c];
        #pragma unroll
        for (int j = 0; j < 8; j++) {
            const float xv = xs[half * 8 + j][k];
            aq[j] = fmaf(xv, wq, aq[j]);
            ak[j] = fmaf(xv, wk, ak[j]);
            av[j] = fmaf(xv, wv, av[j]);
        }
    }
    const float bqv = bq[c], bkv = bk[c], bvv = bv[c];
    #pragma unroll
    for (int j = 0; j < 8; j++) {
        const int n = n0 + half * 8 + j;
        Q[n * C + c] = aq[j] + bqv;
        K[n * C + c] = ak[j] + bkv;
        V[n * C + c] = av[j] + bvv;
    }
}

// ---------------- adjacency bitmask build (dedupes edges) ----------------
__global__ __launch_bounds__(256) void mask_kernel(
    const int* __restrict__ ei, unsigned int* __restrict__ mask)
{
    const int e = blockIdx.x * 256 + threadIdx.x;
    if (e < NE) {
        int src = ei[e];
        int dst = ei[NE + e];
        src = src < 0 ? 0 : (src > NN - 1 ? NN - 1 : src);
        dst = dst < 0 ? 0 : (dst > NN - 1 ? NN - 1 : dst);
        atomicOr(&mask[(src * NN + dst) >> 5], 1u << (dst & 31));
    }
}

// ---------------- sparse attention: 1 wave (64 lanes) per node ----------------
// lane = sub*8 + h : 8 lanes per head, 8 heads.
__global__ __launch_bounds__(64) void attn_kernel(
    const float* __restrict__ Q, const float* __restrict__ K,
    const float* __restrict__ V, const unsigned int* __restrict__ mask,
    float* __restrict__ attn_out)
{
    __shared__ unsigned short nb[NN];
    __shared__ int cnt_s;
    const int n = blockIdx.x;
    const int lane = threadIdx.x;
    if (lane == 0) cnt_s = 0;
    __syncthreads();

    // enumerate neighbor set from bitmask row (128 x u32 words)
    const unsigned int* row = mask + n * (NN / 32);
    #pragma unroll
    for (int j = 0; j < 2; j++) {
        const int w = lane * 2 + j;
        unsigned int bits = row[w];
        if (bits) {
            int off = atomicAdd(&cnt_s, __popc(bits));
            while (bits) {
                const int b = __ffs(bits) - 1;
                bits &= bits - 1;
                nb[off++] = (unsigned short)(w * 32 + b);
            }
        }
    }
    __syncthreads();
    const int deg = cnt_s;
    const int h = lane & 7;
    const int sub = lane >> 3;

    // Q fragment for this head
    float qh[16];
    {
        const float4* qp = reinterpret_cast<const float4*>(Q + n * C + h * HD);
        const float4 q0 = qp[0], q1 = qp[1], q2 = qp[2], q3 = qp[3];
        qh[0]=q0.x; qh[1]=q0.y; qh[2]=q0.z; qh[3]=q0.w;
        qh[4]=q1.x; qh[5]=q1.y; qh[6]=q1.z; qh[7]=q1.w;
        qh[8]=q2.x; qh[9]=q2.y; qh[10]=q2.z; qh[11]=q2.w;
        qh[12]=q3.x; qh[13]=q3.y; qh[14]=q3.z; qh[15]=q3.w;
    }

    // pass A: online max + sum of exp
    float mmax = -INFINITY, ssum = 0.f;
    for (int i = sub; i < deg; i += 8) {
        const int m = nb[i];
        const float4* kp = reinterpret_cast<const float4*>(K + m * C + h * HD);
        const float4 k0 = kp[0], k1 = kp[1], k2 = kp[2], k3 = kp[3];
        float s = qh[0]*k0.x + qh[1]*k0.y + qh[2]*k0.z + qh[3]*k0.w
                + qh[4]*k1.x + qh[5]*k1.y + qh[6]*k1.z + qh[7]*k1.w
                + qh[8]*k2.x + qh[9]*k2.y + qh[10]*k2.z + qh[11]*k2.w
                + qh[12]*k3.x + qh[13]*k3.y + qh[14]*k3.z + qh[15]*k3.w;
        s *= 0.25f;
        const float nm = fmaxf(mmax, s);
        ssum = ssum * __expf(mmax - nm) + __expf(s - nm);
        mmax = nm;
    }
    // butterfly combine across the 8 sub-lanes of each head
    #pragma unroll
    for (int off = 8; off < 64; off <<= 1) {
        const float omax = __shfl_xor(mmax, off, 64);
        const float osum = __shfl_xor(ssum, off, 64);
        const float nm = fmaxf(mmax, omax);
        if (nm != -INFINITY)
            ssum = ssum * __expf(mmax - nm) + osum * __expf(omax - nm);
        else
            ssum = ssum + osum;
        mmax = nm;
    }

    const float inv = (ssum > 0.f) ? 1.f / ssum : 0.f;

    // pass B: recompute score, accumulate p * V
    float acc[16];
    #pragma unroll
    for (int d = 0; d < 16; d++) acc[d] = 0.f;
    for (int i = sub; i < deg; i += 8) {
        const int m = nb[i];
        const float4* kp = reinterpret_cast<const float4*>(K + m * C + h * HD);
        const float4 k0 = kp[0], k1 = kp[1], k2 = kp[2], k3 = kp[3];
        float s = qh[0]*k0.x + qh[1]*k0.y + qh[2]*k0.z + qh[3]*k0.w
                + qh[4]*k1.x + qh[5]*k1.y + qh[6]*k1.z + qh[7]*k1.w
                + qh[8]*k2.x + qh[9]*k2.y + qh[10]*k2.z + qh[11]*k2.w
                + qh[12]*k3.x + qh[13]*k3.y + qh[14]*k3.z + qh[15]*k3.w;
        const float p = __expf(s * 0.25f - mmax) * inv;
        const float4* vp = reinterpret_cast<const float4*>(V + m * C + h * HD);
        const float4 v0 = vp[0], v1 = vp[1], v2 = vp[2], v3 = vp[3];
        acc[0]  = fmaf(p, v0.x, acc[0]);  acc[1]  = fmaf(p, v0.y, acc[1]);
        acc[2]  = fmaf(p, v0.z, acc[2]);  acc[3]  = fmaf(p, v0.w, acc[3]);
        acc[4]  = fmaf(p, v1.x, acc[4]);  acc[5]  = fmaf(p, v1.y, acc[5]);
        acc[6]  = fmaf(p, v1.z, acc[6]);  acc[7]  = fmaf(p, v1.w, acc[7]);
        acc[8]  = fmaf(p, v2.x, acc[8]);  acc[9]  = fmaf(p, v2.y, acc[9]);
        acc[10] = fmaf(p, v2.z, acc[10]); acc[11] = fmaf(p, v2.w, acc[11]);
        acc[12] = fmaf(p, v3.x, acc[12]); acc[13] = fmaf(p, v3.y, acc[13]);
        acc[14] = fmaf(p, v3.z, acc[14]); acc[15] = fmaf(p, v3.w, acc[15]);
    }
    #pragma unroll
    for (int off = 8; off < 64; off <<= 1) {
        #pragma unroll
        for (int d = 0; d < 16; d++)
            acc[d] += __shfl_xor(acc[d], off, 64);
    }

    if (deg > 0) {
        if (sub == 0) {
            float4* op = reinterpret_cast<float4*>(attn_out + n * C + h * HD);
            op[0] = make_float4(acc[0],  acc[1],  acc[2],  acc[3]);
            op[1] = make_float4(acc[4],  acc[5],  acc[6],  acc[7]);
            op[2] = make_float4(acc[8],  acc[9],  acc[10], acc[11]);
            op[3] = make_float4(acc[12], acc[13], acc[14], acc[15]);
        }
    } else {
        // all-masked row: attention = 1/n uniform -> mean of V per channel
        float s0 = 0.f, s1 = 0.f;
        for (int m = 0; m < NN; m++) {
            s0 += V[m * C + lane];
            s1 += V[m * C + 64 + lane];
        }
        attn_out[n * C + lane]      = s0 * (1.f / (float)NN);
        attn_out[n * C + 64 + lane] = s1 * (1.f / (float)NN);
    }
}

// ---------------- output projection: out = attn @ Wo + bo ----------------
__global__ __launch_bounds__(256) void proj_kernel(
    const float* __restrict__ a, const float* __restrict__ Wo,
    const float* __restrict__ bo, float* __restrict__ out)
{
    __shared__ float as[16][C];
    const int n0 = blockIdx.x * 16;
    for (int i = threadIdx.x; i < 16 * C; i += 256)
        as[i >> 7][i & 127] = a[n0 * C + i];
    __syncthreads();

    const int c = threadIdx.x & 127;
    const int half = threadIdx.x >> 7;
    float ac[8];
    #pragma unroll
    for (int j = 0; j < 8; j++) ac[j] = 0.f;
    for (int k = 0; k < C; k++) {
        const float w = Wo[k * C + c];
        #pragma unroll
        for (int j = 0; j < 8; j++)
            ac[j] = fmaf(as[half * 8 + j][k], w, ac[j]);
    }
    const float bv = bo[c];
    #pragma unroll
    for (int j = 0; j < 8; j++)
        out[(n0 + half * 8 + j) * C + c] = ac[j] + bv;
}

extern "C" void kernel_launch(void* const* d_in, const int* in_sizes, int n_in,
                              void* d_out, int out_size, void* d_ws, size_t ws_size,
                              hipStream_t stream)
{
    const float* x  = (const float*)d_in[0];
    const int*   ei = (const int*)d_in[1];
    const float* Wq = (const float*)d_in[2];
    const float* bq = (const float*)d_in[3];
    const float* Wk = (const float*)d_in[4];
    const float* bk = (const float*)d_in[5];
    const float* Wv = (const float*)d_in[6];
    const float* bv = (const float*)d_in[7];
    const float* Wo = (const float*)d_in[8];
    const float* bo = (const float*)d_in[9];
    float* out = (float*)d_out;

    char* ws = (char*)d_ws;
    const size_t MB2 = 1u << 21;           // 2 MiB = 4096*128*4
    float*        Q    = (float*)(ws);
    float*        K    = (float*)(ws + MB2);
    float*        V    = (float*)(ws + 2 * MB2);
    float*        attn = (float*)(ws + 3 * MB2);
    unsigned int* mask = (unsigned int*)(ws + 4 * MB2);

    // mask clear is fused into qkv_kernel (each block zeroes its 8 KiB slice);
    // mask_kernel is ordered after qkv_kernel on `stream`, so the clear is complete.
    qkv_kernel<<<NN / 16, 256, 0, stream>>>(x, Wq, bq, Wk, bk, Wv, bv, Q, K, V,
                                            (float4*)mask);
    mask_kernel<<<NE / 256, 256, 0, stream>>>(ei, mask);
    attn_kernel<<<NN, 64, 0, stream>>>(Q, K, V, mask, attn);
    proj_kernel<<<NN / 16, 256, 0, stream>>>(attn, Wo, bo, out);
}